// Round 1
// baseline (4419.682 us; speedup 1.0000x reference)
//
#include <hip/hip_runtime.h>

#define D 64

// deg[src[e]] += 1
__global__ __launch_bounds__(256) void deg_kernel(const int* __restrict__ src,
                                                  float* __restrict__ deg, int E) {
    int e = blockIdx.x * 256 + threadIdx.x;
    if (e < E) atomicAdd(&deg[src[e]], 1.0f);
}

// deg -> 1/max(deg,1) in place
__global__ __launch_bounds__(256) void inv_kernel(float* __restrict__ deg, int N) {
    int n = blockIdx.x * 256 + threadIdx.x;
    if (n < N) deg[n] = 1.0f / fmaxf(deg[n], 1.0f);
}

// agg[dst[e]][:] += h[src[e]][:] * dinv[src[e]]   (16 threads per edge, float4 each)
__global__ __launch_bounds__(256) void scatter_kernel(const float* __restrict__ h,
                                                      const float* __restrict__ dinv,
                                                      const int* __restrict__ src,
                                                      const int* __restrict__ dst,
                                                      float* __restrict__ agg, int E) {
    int idx = blockIdx.x * 256 + threadIdx.x;
    int e = idx >> 4, q = idx & 15;
    if (e >= E) return;
    int s = src[e];
    int t = dst[e];
    float sc = dinv[s];
    const float4 v = *(const float4*)(h + (size_t)s * D + q * 4);
    float* a = agg + (size_t)t * D + q * 4;
    atomicAdd(a + 0, v.x * sc);
    atomicAdd(a + 1, v.y * sc);
    atomicAdd(a + 2, v.z * sc);
    atomicAdd(a + 3, v.w * sc);
}

// out[r][j] = act(sum_k A[r][k] * W[k][j] + b[j]); wave per row, lane per column.
__global__ __launch_bounds__(256) void gemm_kernel(const float* __restrict__ A,
                                                   const float* __restrict__ W,
                                                   const float* __restrict__ bias,
                                                   float* __restrict__ out, int N, int doRelu) {
    __shared__ float Ws[D * D];
    __shared__ float bs[D];
    int tid = threadIdx.x;
#pragma unroll
    for (int i = 0; i < 16; ++i) Ws[tid + i * 256] = W[tid + i * 256];
    if (tid < D) bs[tid] = bias[tid];
    __syncthreads();
    int wave = tid >> 6, lane = tid & 63;
    for (int base = blockIdx.x * 4; base < N; base += gridDim.x * 4) {
        int r = base + wave;
        if (r < N) {
            const float4* Arow = (const float4*)(A + (size_t)r * D);
            float acc = bs[lane];
#pragma unroll
            for (int k4 = 0; k4 < 16; ++k4) {
                float4 a = Arow[k4];
                acc = fmaf(a.x, Ws[(k4 * 4 + 0) * D + lane], acc);
                acc = fmaf(a.y, Ws[(k4 * 4 + 1) * D + lane], acc);
                acc = fmaf(a.z, Ws[(k4 * 4 + 2) * D + lane], acc);
                acc = fmaf(a.w, Ws[(k4 * 4 + 3) * D + lane], acc);
            }
            if (doRelu) acc = fmaxf(acc, 0.0f);
            out[(size_t)r * D + lane] = acc;
        }
    }
}

// msum[j] += sum over rows of h[:, j]
__global__ __launch_bounds__(256) void colsum_kernel(const float* __restrict__ h,
                                                     float* __restrict__ msum, int total) {
    __shared__ float sm[D];
    if (threadIdx.x < D) sm[threadIdx.x] = 0.0f;
    __syncthreads();
    float4 p = make_float4(0.f, 0.f, 0.f, 0.f);
    size_t stride = (size_t)gridDim.x * 256 * 4;  // multiple of 64 -> column-stable
    for (size_t i = ((size_t)blockIdx.x * 256 + threadIdx.x) * 4; i < (size_t)total; i += stride) {
        float4 v = *(const float4*)(h + i);
        p.x += v.x; p.y += v.y; p.z += v.z; p.w += v.w;
    }
    int c = (threadIdx.x * 4) & (D - 1);
    atomicAdd(&sm[c + 0], p.x);
    atomicAdd(&sm[c + 1], p.y);
    atomicAdd(&sm[c + 2], p.z);
    atomicAdd(&sm[c + 3], p.w);
    __syncthreads();
    if (threadIdx.x < D) atomicAdd(&msum[threadIdx.x], sm[threadIdx.x]);
}

__global__ void finalize_kernel(const float* __restrict__ msum, float* __restrict__ outMean,
                                float invN) {
    int j = threadIdx.x;
    outMean[j] = msum[j] * invN;
}

extern "C" void kernel_launch(void* const* d_in, const int* in_sizes, int n_in,
                              void* d_out, int out_size, void* d_ws, size_t ws_size,
                              hipStream_t stream) {
    const float* feat = (const float*)d_in[0];
    const int* src = (const int*)d_in[1];
    const int* dst = (const int*)d_in[2];
    const float* W0 = (const float*)d_in[3];
    const float* b0 = (const float*)d_in[4];
    const float* W1 = (const float*)d_in[5];
    const float* b1 = (const float*)d_in[6];
    const float* W2 = (const float*)d_in[7];
    const float* b2 = (const float*)d_in[8];

    const int N = in_sizes[0] / D;  // 100000
    const int E = in_sizes[1];      // 1600000
    float* out = (float*)d_out;     // [N*D + D] floats

    // workspace layout (floats)
    float* ws = (float*)d_ws;
    float* deg = ws;                      // N floats (becomes deg_inv)
    float* msum = ws + 100352;            // 64 floats, 16B-aligned offset
    float* agg = ws + 131072;             // N*D floats
    float* hbuf = agg + (size_t)N * D;    // N*D floats

    hipMemsetAsync(deg, 0, sizeof(float) * (size_t)N, stream);
    hipMemsetAsync(msum, 0, sizeof(float) * D, stream);

    deg_kernel<<<(E + 255) / 256, 256, 0, stream>>>(src, deg, E);
    inv_kernel<<<(N + 255) / 256, 256, 0, stream>>>(deg, N);

    const float* Wl[3] = {W0, W1, W2};
    const float* bl[3] = {b0, b1, b2};
    const float* hin = feat;
    for (int l = 0; l < 3; ++l) {
        hipMemsetAsync(agg, 0, sizeof(float) * (size_t)N * D, stream);
        long long threads = (long long)E * 16;
        scatter_kernel<<<(int)((threads + 255) / 256), 256, 0, stream>>>(hin, deg, src, dst, agg, E);
        float* hout = (l == 2) ? out : hbuf;
        gemm_kernel<<<2048, 256, 0, stream>>>(agg, Wl[l], bl[l], hout, N, l < 2 ? 1 : 0);
        hin = hout;
    }

    colsum_kernel<<<256, 256, 0, stream>>>(out, msum, N * D);
    finalize_kernel<<<1, 64, 0, stream>>>(msum, out + (size_t)N * D, 1.0f / (float)N);
}

// Round 2
// 912.702 us; speedup vs baseline: 4.8424x; 4.8424x over previous
//
#include <hip/hip_runtime.h>

#define D 64

// ---- degree (out-degree over src), float ----
__global__ __launch_bounds__(256) void deg_kernel(const int* __restrict__ src,
                                                  float* __restrict__ deg, int E) {
    int e = blockIdx.x * 256 + threadIdx.x;
    if (e < E) atomicAdd(&deg[src[e]], 1.0f);
}

__global__ __launch_bounds__(256) void inv_kernel(float* __restrict__ deg, int N) {
    int n = blockIdx.x * 256 + threadIdx.x;
    if (n < N) deg[n] = 1.0f / fmaxf(deg[n], 1.0f);
}

// ---- in-degree histogram over dst (int) ----
__global__ __launch_bounds__(256) void hist_kernel(const int* __restrict__ dst,
                                                   int* __restrict__ cnt, int E) {
    int e = blockIdx.x * 256 + threadIdx.x;
    if (e < E) atomicAdd(&cnt[dst[e]], 1);
}

// ---- single-workgroup exclusive scan: cnt[N] -> row_ptr[N+1], cursor=row_ptr ----
__global__ __launch_bounds__(1024) void scan_kernel(const int* __restrict__ cnt,
                                                    int* __restrict__ row_ptr,
                                                    int* __restrict__ cursor, int N) {
    __shared__ int sdata[1024];
    __shared__ int carry;
    if (threadIdx.x == 0) carry = 0;
    __syncthreads();
    for (int base = 0; base < N; base += 1024) {
        int i = base + (int)threadIdx.x;
        int v = (i < N) ? cnt[i] : 0;
        sdata[threadIdx.x] = v;
        __syncthreads();
        for (int off = 1; off < 1024; off <<= 1) {
            int t = (threadIdx.x >= (unsigned)off) ? sdata[threadIdx.x - off] : 0;
            __syncthreads();
            sdata[threadIdx.x] += t;
            __syncthreads();
        }
        int excl = sdata[threadIdx.x] - v + carry;   // reads carry (pre-update)
        if (i < N) { row_ptr[i] = excl; cursor[i] = excl; }
        __syncthreads();
        if (threadIdx.x == 1023) carry += sdata[1023];
        __syncthreads();
    }
    if (threadIdx.x == 0) row_ptr[N] = carry;
}

// ---- CSR fill: col[pos] = src[e] bucketed by dst[e] ----
__global__ __launch_bounds__(256) void fill_kernel(const int* __restrict__ src,
                                                   const int* __restrict__ dst,
                                                   int* __restrict__ cursor,
                                                   int* __restrict__ col, int E) {
    int e = blockIdx.x * 256 + threadIdx.x;
    if (e < E) {
        int pos = atomicAdd(&cursor[dst[e]], 1);
        col[pos] = src[e];
    }
}

// ---- prescale: hs[n][:] = feat[n][:] * dinv[n]  (thread per float4) ----
__global__ __launch_bounds__(256) void prescale_kernel(const float* __restrict__ feat,
                                                       const float* __restrict__ dinv,
                                                       float* __restrict__ hs, int total4) {
    int i = blockIdx.x * 256 + threadIdx.x;
    if (i >= total4) return;
    int n = i >> 4;  // 16 float4 per row
    float sc = dinv[n];
    float4 v = ((const float4*)feat)[i];
    v.x *= sc; v.y *= sc; v.z *= sc; v.w *= sc;
    ((float4*)hs)[i] = v;
}

// ---- gather: agg[n][:] = sum_{j in row} hs[col[j]][:]  (16 lanes x float4 per node) ----
__global__ __launch_bounds__(256) void gather_kernel(const float* __restrict__ hs,
                                                     const int* __restrict__ row_ptr,
                                                     const int* __restrict__ col,
                                                     float* __restrict__ agg, int N) {
    int node = blockIdx.x * 16 + ((int)threadIdx.x >> 4);
    int q = (int)threadIdx.x & 15;
    if (node >= N) return;
    int beg = row_ptr[node], end = row_ptr[node + 1];
    float4 a0 = make_float4(0.f, 0.f, 0.f, 0.f);
    float4 a1 = make_float4(0.f, 0.f, 0.f, 0.f);
    int j = beg;
    for (; j + 1 < end; j += 2) {
        int s0 = col[j];
        int s1 = col[j + 1];
        float4 v0 = *(const float4*)(hs + (size_t)s0 * D + q * 4);
        float4 v1 = *(const float4*)(hs + (size_t)s1 * D + q * 4);
        a0.x += v0.x; a0.y += v0.y; a0.z += v0.z; a0.w += v0.w;
        a1.x += v1.x; a1.y += v1.y; a1.z += v1.z; a1.w += v1.w;
    }
    if (j < end) {
        int s0 = col[j];
        float4 v0 = *(const float4*)(hs + (size_t)s0 * D + q * 4);
        a0.x += v0.x; a0.y += v0.y; a0.z += v0.z; a0.w += v0.w;
    }
    a0.x += a1.x; a0.y += a1.y; a0.z += a1.z; a0.w += a1.w;
    *(float4*)(agg + (size_t)node * D + q * 4) = a0;
}

// ---- GEMM: out[r][j] = epilogue(sum_k A[r][k]*W[k][j] + b[j]) ----
// mode 0: write relu(acc)*dinv[r]  (scaled hidden for next layer's gather)
// mode 1: write acc unscaled       (final layer output)
__global__ __launch_bounds__(256) void gemm_kernel(const float* __restrict__ A,
                                                   const float* __restrict__ W,
                                                   const float* __restrict__ bias,
                                                   const float* __restrict__ dinv,
                                                   float* __restrict__ out, int N, int mode) {
    __shared__ float Ws[D * D];
    __shared__ float bs[D];
    int tid = threadIdx.x;
#pragma unroll
    for (int i = 0; i < 16; ++i) Ws[tid + i * 256] = W[tid + i * 256];
    if (tid < D) bs[tid] = bias[tid];
    __syncthreads();
    int wave = tid >> 6, lane = tid & 63;
    for (int base = blockIdx.x * 4; base < N; base += gridDim.x * 4) {
        int r = base + wave;
        if (r < N) {
            const float4* Arow = (const float4*)(A + (size_t)r * D);
            float acc = bs[lane];
#pragma unroll
            for (int k4 = 0; k4 < 16; ++k4) {
                float4 a = Arow[k4];
                acc = fmaf(a.x, Ws[(k4 * 4 + 0) * D + lane], acc);
                acc = fmaf(a.y, Ws[(k4 * 4 + 1) * D + lane], acc);
                acc = fmaf(a.z, Ws[(k4 * 4 + 2) * D + lane], acc);
                acc = fmaf(a.w, Ws[(k4 * 4 + 3) * D + lane], acc);
            }
            if (mode == 0) acc = fmaxf(acc, 0.0f) * dinv[r];
            out[(size_t)r * D + lane] = acc;
        }
    }
}

// ---- column-mean over final h ----
__global__ __launch_bounds__(256) void colsum_kernel(const float* __restrict__ h,
                                                     float* __restrict__ msum, int total) {
    __shared__ float sm[D];
    if (threadIdx.x < D) sm[threadIdx.x] = 0.0f;
    __syncthreads();
    float4 p = make_float4(0.f, 0.f, 0.f, 0.f);
    size_t stride = (size_t)gridDim.x * 256 * 4;
    for (size_t i = ((size_t)blockIdx.x * 256 + threadIdx.x) * 4; i < (size_t)total; i += stride) {
        float4 v = *(const float4*)(h + i);
        p.x += v.x; p.y += v.y; p.z += v.z; p.w += v.w;
    }
    int c = (threadIdx.x * 4) & (D - 1);
    atomicAdd(&sm[c + 0], p.x);
    atomicAdd(&sm[c + 1], p.y);
    atomicAdd(&sm[c + 2], p.z);
    atomicAdd(&sm[c + 3], p.w);
    __syncthreads();
    if (threadIdx.x < D) atomicAdd(&msum[threadIdx.x], sm[threadIdx.x]);
}

__global__ void finalize_kernel(const float* __restrict__ msum, float* __restrict__ outMean,
                                float invN) {
    outMean[threadIdx.x] = msum[threadIdx.x] * invN;
}

extern "C" void kernel_launch(void* const* d_in, const int* in_sizes, int n_in,
                              void* d_out, int out_size, void* d_ws, size_t ws_size,
                              hipStream_t stream) {
    const float* feat = (const float*)d_in[0];
    const int* src = (const int*)d_in[1];
    const int* dst = (const int*)d_in[2];
    const float* W0 = (const float*)d_in[3];
    const float* b0 = (const float*)d_in[4];
    const float* W1 = (const float*)d_in[5];
    const float* b1 = (const float*)d_in[6];
    const float* W2 = (const float*)d_in[7];
    const float* b2 = (const float*)d_in[8];

    const int N = in_sizes[0] / D;  // 100000
    const int E = in_sizes[1];      // 1600000
    float* out = (float*)d_out;     // [N*D + D] floats

    // workspace layout (4-byte units), all offsets 16B-aligned
    char* wsb = (char*)d_ws;
    const size_t NA = 100352;  // padded N
    float* deg     = (float*)wsb;                             // NA
    int*   row_ptr = (int*)(wsb + NA * 4);                    // NA (incl. +1 slot)
    int*   cursor  = (int*)(wsb + 2 * NA * 4);                // NA  (doubles as cnt)
    float* msum    = (float*)(wsb + 3 * NA * 4);              // 64 (+pad 256)
    int*   col     = (int*)(wsb + (3 * NA + 256) * 4);        // E
    float* hs      = (float*)(wsb + (3 * NA + 256 + 1600000) * 4);          // N*D
    float* agg     = hs + (size_t)N * D;                                    // N*D

    hipMemsetAsync(deg, 0, sizeof(float) * NA, stream);
    hipMemsetAsync(cursor, 0, sizeof(int) * NA, stream);
    hipMemsetAsync(msum, 0, sizeof(float) * D, stream);

    const int EB = (E + 255) / 256;
    const int NB = (N + 255) / 256;

    deg_kernel<<<EB, 256, 0, stream>>>(src, deg, E);
    inv_kernel<<<NB, 256, 0, stream>>>(deg, N);

    // CSR by destination
    hist_kernel<<<EB, 256, 0, stream>>>(dst, cursor, E);          // cursor = cnt
    scan_kernel<<<1, 1024, 0, stream>>>(cursor, row_ptr, cursor, N);
    fill_kernel<<<EB, 256, 0, stream>>>(src, dst, cursor, col, E);

    // hs = feat * dinv
    prescale_kernel<<<(N * 16 + 255) / 256, 256, 0, stream>>>(feat, deg, hs, N * 16);

    const float* Wl[3] = {W0, W1, W2};
    const float* bl[3] = {b0, b1, b2};
    const int GB = (N + 15) / 16;
    for (int l = 0; l < 3; ++l) {
        gather_kernel<<<GB, 256, 0, stream>>>(hs, row_ptr, col, agg, N);
        float* hout = (l == 2) ? out : hs;  // layers 0,1 write scaled hidden back to hs
        gemm_kernel<<<2048, 256, 0, stream>>>(agg, Wl[l], bl[l], deg, hout, N, l < 2 ? 0 : 1);
    }

    colsum_kernel<<<256, 256, 0, stream>>>(out, msum, N * D);
    finalize_kernel<<<1, 64, 0, stream>>>(msum, out + (size_t)N * D, 1.0f / (float)N);
}

// Round 3
// 710.135 us; speedup vs baseline: 6.2237x; 1.2853x over previous
//
#include <hip/hip_runtime.h>

#define D 64

// ---- fused histograms: out-degree over src (int) + in-degree over dst (int) ----
__global__ __launch_bounds__(256) void hist2_kernel(const int* __restrict__ src,
                                                    const int* __restrict__ dst,
                                                    int* __restrict__ outdeg,
                                                    int* __restrict__ cnt, int E) {
    int e = blockIdx.x * 256 + threadIdx.x;
    if (e < E) {
        atomicAdd(&outdeg[src[e]], 1);
        atomicAdd(&cnt[dst[e]], 1);
    }
}

// int out-degree -> float 1/max(deg,1) in place (aliased buffer)
__global__ __launch_bounds__(256) void inv_kernel(float* __restrict__ deg, int N) {
    int n = blockIdx.x * 256 + threadIdx.x;
    if (n < N) {
        float d = (float)((const int*)deg)[n];
        deg[n] = 1.0f / fmaxf(d, 1.0f);
    }
}

// ---- scan stage A: per-1024-chunk sums ----
__global__ __launch_bounds__(256) void blocksum_kernel(const int* __restrict__ cnt,
                                                       int* __restrict__ bsum, int N) {
    int i = blockIdx.x * 1024 + (int)threadIdx.x * 4;
    int s = 0;
    if (i + 3 < N) {
        int4 v = *(const int4*)(cnt + i);
        s = v.x + v.y + v.z + v.w;
    } else {
        for (int k = 0; k < 4; ++k) if (i + k < N) s += cnt[i + k];
    }
#pragma unroll
    for (int d = 1; d < 64; d <<= 1) s += __shfl_down(s, d);
    __shared__ int ws[4];
    int lane = (int)threadIdx.x & 63, wv = (int)threadIdx.x >> 6;
    if (lane == 0) ws[wv] = s;
    __syncthreads();
    if (threadIdx.x == 0) bsum[blockIdx.x] = ws[0] + ws[1] + ws[2] + ws[3];
}

// ---- scan stage B: exclusive-scan the (<=128) block sums; write total to row_ptr[N] ----
__global__ __launch_bounds__(128) void bscan_kernel(int* __restrict__ bsum,
                                                    int* __restrict__ total_out, int nb) {
    int tid = (int)threadIdx.x;
    int v = (tid < nb) ? bsum[tid] : 0;
    int x = v;
    int lane = tid & 63;
#pragma unroll
    for (int d = 1; d < 64; d <<= 1) {
        int t = __shfl_up(x, d);
        if (lane >= d) x += t;
    }
    __shared__ int w0;
    if (tid == 63) w0 = x;
    __syncthreads();
    if (tid >= 64) x += w0;
    if (tid < nb) bsum[tid] = x - v;  // exclusive
    if (tid == nb - 1) *total_out = x;
}

// ---- scan stage C: per-chunk scan + block offset -> row_ptr, cursor ----
__global__ __launch_bounds__(256) void scanchunk_kernel(const int* __restrict__ cnt,
                                                        const int* __restrict__ bsum,
                                                        int* __restrict__ row_ptr,
                                                        int* __restrict__ cursor, int N) {
    int i = blockIdx.x * 1024 + (int)threadIdx.x * 4;
    int v0 = 0, v1 = 0, v2 = 0, v3 = 0;
    bool full = (i + 3 < N);
    if (full) {
        int4 v = *(const int4*)(cnt + i);
        v0 = v.x; v1 = v.y; v2 = v.z; v3 = v.w;
    } else {
        if (i < N) v0 = cnt[i];
        if (i + 1 < N) v1 = cnt[i + 1];
        if (i + 2 < N) v2 = cnt[i + 2];
    }
    int s = v0 + v1 + v2 + v3;
    int x = s;
    int lane = (int)threadIdx.x & 63, wv = (int)threadIdx.x >> 6;
#pragma unroll
    for (int d = 1; d < 64; d <<= 1) {
        int t = __shfl_up(x, d);
        if (lane >= d) x += t;
    }
    __shared__ int wtot[4];
    __shared__ int wexcl[4];
    if (lane == 63) wtot[wv] = x;
    __syncthreads();
    if (threadIdx.x == 0) {
        int a = 0;
#pragma unroll
        for (int k = 0; k < 4; ++k) { wexcl[k] = a; a += wtot[k]; }
    }
    __syncthreads();
    int p0 = (x - s) + wexcl[wv] + bsum[blockIdx.x];
    int p1 = p0 + v0, p2 = p1 + v1, p3 = p2 + v2;
    if (full) {
        int4 r = make_int4(p0, p1, p2, p3);
        *(int4*)(row_ptr + i) = r;
        *(int4*)(cursor + i) = r;
    } else {
        if (i < N) { row_ptr[i] = p0; cursor[i] = p0; }
        if (i + 1 < N) { row_ptr[i + 1] = p1; cursor[i + 1] = p1; }
        if (i + 2 < N) { row_ptr[i + 2] = p2; cursor[i + 2] = p2; }
    }
}

// ---- CSR fill: col[pos] = src[e] bucketed by dst[e] ----
__global__ __launch_bounds__(256) void fill_kernel(const int* __restrict__ src,
                                                   const int* __restrict__ dst,
                                                   int* __restrict__ cursor,
                                                   int* __restrict__ col, int E) {
    int e = blockIdx.x * 256 + threadIdx.x;
    if (e < E) {
        int pos = atomicAdd(&cursor[dst[e]], 1);
        col[pos] = src[e];
    }
}

// ---- prescale: hs[n][:] = feat[n][:] * dinv[n] ----
__global__ __launch_bounds__(256) void prescale_kernel(const float* __restrict__ feat,
                                                       const float* __restrict__ dinv,
                                                       float* __restrict__ hs, int total4) {
    int i = blockIdx.x * 256 + threadIdx.x;
    if (i >= total4) return;
    int n = i >> 4;
    float sc = dinv[n];
    float4 v = ((const float4*)feat)[i];
    v.x *= sc; v.y *= sc; v.z *= sc; v.w *= sc;
    ((float4*)hs)[i] = v;
}

// ---- gather: agg[n][:] = sum_{j in row} hs[col[j]][:] ----
__global__ __launch_bounds__(256) void gather_kernel(const float* __restrict__ hs,
                                                     const int* __restrict__ row_ptr,
                                                     const int* __restrict__ col,
                                                     float* __restrict__ agg, int N) {
    int node = blockIdx.x * 16 + ((int)threadIdx.x >> 4);
    int q = (int)threadIdx.x & 15;
    if (node >= N) return;
    int beg = row_ptr[node], end = row_ptr[node + 1];
    float4 a0 = make_float4(0.f, 0.f, 0.f, 0.f);
    float4 a1 = make_float4(0.f, 0.f, 0.f, 0.f);
    int j = beg;
    for (; j + 1 < end; j += 2) {
        int s0 = col[j];
        int s1 = col[j + 1];
        float4 v0 = *(const float4*)(hs + (size_t)s0 * D + q * 4);
        float4 v1 = *(const float4*)(hs + (size_t)s1 * D + q * 4);
        a0.x += v0.x; a0.y += v0.y; a0.z += v0.z; a0.w += v0.w;
        a1.x += v1.x; a1.y += v1.y; a1.z += v1.z; a1.w += v1.w;
    }
    if (j < end) {
        int s0 = col[j];
        float4 v0 = *(const float4*)(hs + (size_t)s0 * D + q * 4);
        a0.x += v0.x; a0.y += v0.y; a0.z += v0.z; a0.w += v0.w;
    }
    a0.x += a1.x; a0.y += a1.y; a0.z += a1.z; a0.w += a1.w;
    *(float4*)(agg + (size_t)node * D + q * 4) = a0;
}

// ---- GEMM: mode 0 -> relu(acc)*dinv[r]; mode 1 -> acc ----
__global__ __launch_bounds__(256) void gemm_kernel(const float* __restrict__ A,
                                                   const float* __restrict__ W,
                                                   const float* __restrict__ bias,
                                                   const float* __restrict__ dinv,
                                                   float* __restrict__ out, int N, int mode) {
    __shared__ float Ws[D * D];
    __shared__ float bs[D];
    int tid = threadIdx.x;
#pragma unroll
    for (int i = 0; i < 16; ++i) Ws[tid + i * 256] = W[tid + i * 256];
    if (tid < D) bs[tid] = bias[tid];
    __syncthreads();
    int wave = tid >> 6, lane = tid & 63;
    for (int base = blockIdx.x * 4; base < N; base += gridDim.x * 4) {
        int r = base + wave;
        if (r < N) {
            const float4* Arow = (const float4*)(A + (size_t)r * D);
            float acc = bs[lane];
#pragma unroll
            for (int k4 = 0; k4 < 16; ++k4) {
                float4 a = Arow[k4];
                acc = fmaf(a.x, Ws[(k4 * 4 + 0) * D + lane], acc);
                acc = fmaf(a.y, Ws[(k4 * 4 + 1) * D + lane], acc);
                acc = fmaf(a.z, Ws[(k4 * 4 + 2) * D + lane], acc);
                acc = fmaf(a.w, Ws[(k4 * 4 + 3) * D + lane], acc);
            }
            if (mode == 0) acc = fmaxf(acc, 0.0f) * dinv[r];
            out[(size_t)r * D + lane] = acc;
        }
    }
}

// ---- column-mean over final h ----
__global__ __launch_bounds__(256) void colsum_kernel(const float* __restrict__ h,
                                                     float* __restrict__ msum, int total) {
    __shared__ float sm[D];
    if (threadIdx.x < D) sm[threadIdx.x] = 0.0f;
    __syncthreads();
    float4 p = make_float4(0.f, 0.f, 0.f, 0.f);
    size_t stride = (size_t)gridDim.x * 256 * 4;
    for (size_t i = ((size_t)blockIdx.x * 256 + threadIdx.x) * 4; i < (size_t)total; i += stride) {
        float4 v = *(const float4*)(h + i);
        p.x += v.x; p.y += v.y; p.z += v.z; p.w += v.w;
    }
    int c = (threadIdx.x * 4) & (D - 1);
    atomicAdd(&sm[c + 0], p.x);
    atomicAdd(&sm[c + 1], p.y);
    atomicAdd(&sm[c + 2], p.z);
    atomicAdd(&sm[c + 3], p.w);
    __syncthreads();
    if (threadIdx.x < D) atomicAdd(&msum[threadIdx.x], sm[threadIdx.x]);
}

__global__ void finalize_kernel(const float* __restrict__ msum, float* __restrict__ outMean,
                                float invN) {
    outMean[threadIdx.x] = msum[threadIdx.x] * invN;
}

extern "C" void kernel_launch(void* const* d_in, const int* in_sizes, int n_in,
                              void* d_out, int out_size, void* d_ws, size_t ws_size,
                              hipStream_t stream) {
    const float* feat = (const float*)d_in[0];
    const int* src = (const int*)d_in[1];
    const int* dst = (const int*)d_in[2];
    const float* W0 = (const float*)d_in[3];
    const float* b0 = (const float*)d_in[4];
    const float* W1 = (const float*)d_in[5];
    const float* b1 = (const float*)d_in[6];
    const float* W2 = (const float*)d_in[7];
    const float* b2 = (const float*)d_in[8];

    const int N = in_sizes[0] / D;  // 100000
    const int E = in_sizes[1];      // 1600000
    float* out = (float*)d_out;     // [N*D + D] floats

    // workspace layout (4-byte units), offsets 16B-aligned; NA = padded N
    char* wsb = (char*)d_ws;
    const size_t NA = 100352;
    float* deg     = (float*)wsb;                              // NA (int counts, then float dinv)
    int*   row_ptr = (int*)(wsb + NA * 4);                     // NA (incl. +1 slot)
    int*   cursor  = (int*)(wsb + 2 * NA * 4);                 // NA (doubles as cnt)
    float* msum    = (float*)(wsb + 3 * NA * 4);               // 64
    int*   bsum    = (int*)(wsb + (3 * NA + 64) * 4);          // 128
    int*   col     = (int*)(wsb + (3 * NA + 256) * 4);         // E
    float* hs      = (float*)(wsb + (3 * NA + 256 + 1600000) * 4);  // N*D
    float* agg     = hs + (size_t)N * D;                            // N*D

    hipMemsetAsync(deg, 0, sizeof(int) * NA, stream);
    hipMemsetAsync(cursor, 0, sizeof(int) * NA, stream);
    hipMemsetAsync(msum, 0, sizeof(float) * D, stream);

    const int EB = (E + 255) / 256;
    const int NB = (N + 255) / 256;
    const int nbChunks = (N + 1023) / 1024;  // 98 <= 128

    // histograms: out-degree (src) + in-degree (dst) in one edge pass
    hist2_kernel<<<EB, 256, 0, stream>>>(src, dst, (int*)deg, cursor, E);
    inv_kernel<<<NB, 256, 0, stream>>>(deg, N);

    // device-wide exclusive scan of cursor(=cnt) -> row_ptr, cursor
    blocksum_kernel<<<nbChunks, 256, 0, stream>>>(cursor, bsum, N);
    bscan_kernel<<<1, 128, 0, stream>>>(bsum, row_ptr + N, nbChunks);
    scanchunk_kernel<<<nbChunks, 256, 0, stream>>>(cursor, bsum, row_ptr, cursor, N);

    fill_kernel<<<EB, 256, 0, stream>>>(src, dst, cursor, col, E);

    prescale_kernel<<<(N * 16 + 255) / 256, 256, 0, stream>>>(feat, deg, hs, N * 16);

    const float* Wl[3] = {W0, W1, W2};
    const float* bl[3] = {b0, b1, b2};
    const int GB = (N + 15) / 16;
    for (int l = 0; l < 3; ++l) {
        gather_kernel<<<GB, 256, 0, stream>>>(hs, row_ptr, col, agg, N);
        float* hout = (l == 2) ? out : hs;
        gemm_kernel<<<2048, 256, 0, stream>>>(agg, Wl[l], bl[l], deg, hout, N, l < 2 ? 0 : 1);
    }

    colsum_kernel<<<256, 256, 0, stream>>>(out, msum, N * D);
    finalize_kernel<<<1, 64, 0, stream>>>(msum, out + (size_t)N * D, 1.0f / (float)N);
}

// Round 4
// 630.641 us; speedup vs baseline: 7.0082x; 1.1261x over previous
//
#include <hip/hip_runtime.h>

#define D 64

// ---- fused histograms: out-degree over src (int) + in-degree over dst (int) ----
__global__ __launch_bounds__(256) void hist2_kernel(const int* __restrict__ src,
                                                    const int* __restrict__ dst,
                                                    int* __restrict__ outdeg,
                                                    int* __restrict__ cnt, int E) {
    int e = blockIdx.x * 256 + threadIdx.x;
    if (e < E) {
        atomicAdd(&outdeg[src[e]], 1);
        atomicAdd(&cnt[dst[e]], 1);
    }
}

// int out-degree -> float 1/max(deg,1) in place (aliased buffer)
__global__ __launch_bounds__(256) void inv_kernel(float* __restrict__ deg, int N) {
    int n = blockIdx.x * 256 + threadIdx.x;
    if (n < N) {
        float d = (float)((const int*)deg)[n];
        deg[n] = 1.0f / fmaxf(d, 1.0f);
    }
}

// ---- scan stage A: per-1024-chunk sums ----
__global__ __launch_bounds__(256) void blocksum_kernel(const int* __restrict__ cnt,
                                                       int* __restrict__ bsum, int N) {
    int i = blockIdx.x * 1024 + (int)threadIdx.x * 4;
    int s = 0;
    if (i + 3 < N) {
        int4 v = *(const int4*)(cnt + i);
        s = v.x + v.y + v.z + v.w;
    } else {
        for (int k = 0; k < 4; ++k) if (i + k < N) s += cnt[i + k];
    }
#pragma unroll
    for (int d = 1; d < 64; d <<= 1) s += __shfl_down(s, d);
    __shared__ int ws[4];
    int lane = (int)threadIdx.x & 63, wv = (int)threadIdx.x >> 6;
    if (lane == 0) ws[wv] = s;
    __syncthreads();
    if (threadIdx.x == 0) bsum[blockIdx.x] = ws[0] + ws[1] + ws[2] + ws[3];
}

// ---- scan stage B: exclusive-scan the (<=128) block sums; total -> row_ptr[N] ----
__global__ __launch_bounds__(128) void bscan_kernel(int* __restrict__ bsum,
                                                    int* __restrict__ total_out, int nb) {
    int tid = (int)threadIdx.x;
    int v = (tid < nb) ? bsum[tid] : 0;
    int x = v;
    int lane = tid & 63;
#pragma unroll
    for (int d = 1; d < 64; d <<= 1) {
        int t = __shfl_up(x, d);
        if (lane >= d) x += t;
    }
    __shared__ int w0;
    if (tid == 63) w0 = x;
    __syncthreads();
    if (tid >= 64) x += w0;
    if (tid < nb) bsum[tid] = x - v;  // exclusive
    if (tid == nb - 1) *total_out = x;
}

// ---- scan stage C: per-chunk scan + block offset -> row_ptr, cursor ----
__global__ __launch_bounds__(256) void scanchunk_kernel(const int* __restrict__ cnt,
                                                        const int* __restrict__ bsum,
                                                        int* __restrict__ row_ptr,
                                                        int* __restrict__ cursor, int N) {
    int i = blockIdx.x * 1024 + (int)threadIdx.x * 4;
    int v0 = 0, v1 = 0, v2 = 0, v3 = 0;
    bool full = (i + 3 < N);
    if (full) {
        int4 v = *(const int4*)(cnt + i);
        v0 = v.x; v1 = v.y; v2 = v.z; v3 = v.w;
    } else {
        if (i < N) v0 = cnt[i];
        if (i + 1 < N) v1 = cnt[i + 1];
        if (i + 2 < N) v2 = cnt[i + 2];
    }
    int s = v0 + v1 + v2 + v3;
    int x = s;
    int lane = (int)threadIdx.x & 63, wv = (int)threadIdx.x >> 6;
#pragma unroll
    for (int d = 1; d < 64; d <<= 1) {
        int t = __shfl_up(x, d);
        if (lane >= d) x += t;
    }
    __shared__ int wtot[4];
    __shared__ int wexcl[4];
    if (lane == 63) wtot[wv] = x;
    __syncthreads();
    if (threadIdx.x == 0) {
        int a = 0;
#pragma unroll
        for (int k = 0; k < 4; ++k) { wexcl[k] = a; a += wtot[k]; }
    }
    __syncthreads();
    int p0 = (x - s) + wexcl[wv] + bsum[blockIdx.x];
    int p1 = p0 + v0, p2 = p1 + v1, p3 = p2 + v2;
    if (full) {
        int4 r = make_int4(p0, p1, p2, p3);
        *(int4*)(row_ptr + i) = r;
        *(int4*)(cursor + i) = r;
    } else {
        if (i < N) { row_ptr[i] = p0; cursor[i] = p0; }
        if (i + 1 < N) { row_ptr[i + 1] = p1; cursor[i + 1] = p1; }
        if (i + 2 < N) { row_ptr[i + 2] = p2; cursor[i + 2] = p2; }
    }
}

// ---- CSR fill: col[pos] = src[e] bucketed by dst[e] ----
__global__ __launch_bounds__(256) void fill_kernel(const int* __restrict__ src,
                                                   const int* __restrict__ dst,
                                                   int* __restrict__ cursor,
                                                   int* __restrict__ col, int E) {
    int e = blockIdx.x * 256 + threadIdx.x;
    if (e < E) {
        int pos = atomicAdd(&cursor[dst[e]], 1);
        col[pos] = src[e];
    }
}

// ---- prescale: hs[n][:] = feat[n][:] * dinv[n] ----
__global__ __launch_bounds__(256) void prescale_kernel(const float* __restrict__ feat,
                                                       const float* __restrict__ dinv,
                                                       float* __restrict__ hs, int total4) {
    int i = blockIdx.x * 256 + threadIdx.x;
    if (i >= total4) return;
    int n = i >> 4;
    float sc = dinv[n];
    float4 v = ((const float4*)feat)[i];
    v.x *= sc; v.y *= sc; v.z *= sc; v.w *= sc;
    ((float4*)hs)[i] = v;
}

// ---- fused gather + GEMM (+ column-sum on final layer) ----
// Per tile of 16 nodes: wave wv gathers rows 4wv..4wv+3 (16 lanes x float4 each),
// stages tile in LDS, then GEMM with W held in registers (lane c owns column c).
// mode 0: out = relu(agg@W+b) * dinv   (hidden layer, written to ping-pong buf)
// mode 1: out = agg@W+b, and msum[c] += column sums (final layer)
__global__ __launch_bounds__(256) void fused_kernel(const float* __restrict__ hs_in,
                                                    const int* __restrict__ row_ptr,
                                                    const int* __restrict__ col,
                                                    const float* __restrict__ W,
                                                    const float* __restrict__ bias,
                                                    const float* __restrict__ dinv,
                                                    float* __restrict__ out,
                                                    float* __restrict__ msum,
                                                    int N, int mode) {
    int tid = (int)threadIdx.x;
    int lane = tid & 63;
    int wv = tid >> 6;
    int g = tid >> 4, q = tid & 15;

    float Wreg[64];
#pragma unroll
    for (int k = 0; k < 64; ++k) Wreg[k] = W[k * 64 + lane];
    float breg = bias[lane];

    __shared__ float aggT[16][64];   // 4 KB tile
    float colacc = 0.0f;

    int ntiles = (N + 15) >> 4;
    for (int tile = blockIdx.x; tile < ntiles; tile += gridDim.x) {
        int node_g = tile * 16 + g;
        float4 a0 = make_float4(0.f, 0.f, 0.f, 0.f);
        float4 a1 = make_float4(0.f, 0.f, 0.f, 0.f);
        if (node_g < N) {
            int beg = row_ptr[node_g], end = row_ptr[node_g + 1];
            int j = beg;
            for (; j + 1 < end; j += 2) {
                int s0 = col[j], s1 = col[j + 1];
                float4 v0 = *(const float4*)(hs_in + (size_t)s0 * D + q * 4);
                float4 v1 = *(const float4*)(hs_in + (size_t)s1 * D + q * 4);
                a0.x += v0.x; a0.y += v0.y; a0.z += v0.z; a0.w += v0.w;
                a1.x += v1.x; a1.y += v1.y; a1.z += v1.z; a1.w += v1.w;
            }
            if (j < end) {
                int s0 = col[j];
                float4 v0 = *(const float4*)(hs_in + (size_t)s0 * D + q * 4);
                a0.x += v0.x; a0.y += v0.y; a0.z += v0.z; a0.w += v0.w;
            }
            a0.x += a1.x; a0.y += a1.y; a0.z += a1.z; a0.w += a1.w;
        }
        *(float4*)(&aggT[g][q * 4]) = a0;
        __syncthreads();

#pragma unroll
        for (int rr = 0; rr < 4; ++rr) {
            int r = wv * 4 + rr;
            int node = tile * 16 + r;
            if (node < N) {
                float acc = breg;
                const float4* Ar = (const float4*)(&aggT[r][0]);
#pragma unroll
                for (int k4 = 0; k4 < 16; ++k4) {
                    float4 av = Ar[k4];   // broadcast ds_read_b128
                    acc = fmaf(av.x, Wreg[k4 * 4 + 0], acc);
                    acc = fmaf(av.y, Wreg[k4 * 4 + 1], acc);
                    acc = fmaf(av.z, Wreg[k4 * 4 + 2], acc);
                    acc = fmaf(av.w, Wreg[k4 * 4 + 3], acc);
                }
                if (mode == 0) {
                    acc = fmaxf(acc, 0.0f) * dinv[node];
                } else {
                    colacc += acc;
                }
                out[(size_t)node * D + lane] = acc;
            }
        }
        __syncthreads();
    }

    if (mode == 1) {
        __shared__ float red[256];
        red[tid] = colacc;
        __syncthreads();
        if (wv == 0) {
            float s = red[lane] + red[64 + lane] + red[128 + lane] + red[192 + lane];
            atomicAdd(&msum[lane], s);
        }
    }
}

__global__ void finalize_kernel(const float* __restrict__ msum, float* __restrict__ outMean,
                                float invN) {
    outMean[threadIdx.x] = msum[threadIdx.x] * invN;
}

extern "C" void kernel_launch(void* const* d_in, const int* in_sizes, int n_in,
                              void* d_out, int out_size, void* d_ws, size_t ws_size,
                              hipStream_t stream) {
    const float* feat = (const float*)d_in[0];
    const int* src = (const int*)d_in[1];
    const int* dst = (const int*)d_in[2];
    const float* W0 = (const float*)d_in[3];
    const float* b0 = (const float*)d_in[4];
    const float* W1 = (const float*)d_in[5];
    const float* b1 = (const float*)d_in[6];
    const float* W2 = (const float*)d_in[7];
    const float* b2 = (const float*)d_in[8];

    const int N = in_sizes[0] / D;  // 100000
    const int E = in_sizes[1];      // 1600000
    float* out = (float*)d_out;     // [N*D + D] floats

    // workspace layout (4-byte units), offsets 16B-aligned; NA = padded N
    char* wsb = (char*)d_ws;
    const size_t NA = 100352;
    float* deg     = (float*)wsb;                              // NA (int counts -> float dinv)
    int*   row_ptr = (int*)(wsb + NA * 4);                     // NA (incl. +1 slot)
    int*   cursor  = (int*)(wsb + 2 * NA * 4);                 // NA (doubles as cnt)
    float* msum    = (float*)(wsb + 3 * NA * 4);               // 64
    int*   bsum    = (int*)(wsb + (3 * NA + 64) * 4);          // 128
    int*   col     = (int*)(wsb + (3 * NA + 256) * 4);         // E
    float* hsA     = (float*)(wsb + (3 * NA + 256 + 1600000) * 4);  // N*D
    float* hsB     = hsA + (size_t)N * D;                           // N*D

    hipMemsetAsync(deg, 0, sizeof(int) * NA, stream);
    hipMemsetAsync(cursor, 0, sizeof(int) * NA, stream);
    hipMemsetAsync(msum, 0, sizeof(float) * D, stream);

    const int EB = (E + 255) / 256;
    const int NB = (N + 255) / 256;
    const int nbChunks = (N + 1023) / 1024;  // 98 <= 128

    hist2_kernel<<<EB, 256, 0, stream>>>(src, dst, (int*)deg, cursor, E);
    inv_kernel<<<NB, 256, 0, stream>>>(deg, N);

    blocksum_kernel<<<nbChunks, 256, 0, stream>>>(cursor, bsum, N);
    bscan_kernel<<<1, 128, 0, stream>>>(bsum, row_ptr + N, nbChunks);
    scanchunk_kernel<<<nbChunks, 256, 0, stream>>>(cursor, bsum, row_ptr, cursor, N);

    fill_kernel<<<EB, 256, 0, stream>>>(src, dst, cursor, col, E);

    prescale_kernel<<<(N * 16 + 255) / 256, 256, 0, stream>>>(feat, deg, hsA, N * 16);

    const int FG = 1024;  // grid-stride over 6250 tiles
    fused_kernel<<<FG, 256, 0, stream>>>(hsA, row_ptr, col, W0, b0, deg, hsB, msum, N, 0);
    fused_kernel<<<FG, 256, 0, stream>>>(hsB, row_ptr, col, W1, b1, deg, hsA, msum, N, 0);
    fused_kernel<<<FG, 256, 0, stream>>>(hsA, row_ptr, col, W2, b2, deg, out, msum, N, 1);

    finalize_kernel<<<1, 64, 0, stream>>>(msum, out + (size_t)N * D, 1.0f / (float)N);
}

// Round 5
// 455.638 us; speedup vs baseline: 9.7000x; 1.3841x over previous
//
#include <hip/hip_runtime.h>

#define D 64
#define NBUK 391      // ceil(100096/256) buckets of 256 nodes (key >> 8)
#define CHUNK 8192    // edges per block in phase1/phase2

// ---- phase1: per-block coarse histograms. bins [0,NBUK)=dst, [NBUK,2*NBUK)=src ----
__global__ __launch_bounds__(256) void phase1_kernel(const int* __restrict__ src,
                                                     const int* __restrict__ dst,
                                                     int* __restrict__ per_block, int E) {
    __shared__ int h[2 * NBUK];
    int tid = (int)threadIdx.x;
    for (int j = tid; j < 2 * NBUK; j += 256) h[j] = 0;
    __syncthreads();
    int base = blockIdx.x * CHUNK;
    int cnt = min(CHUNK, E - base);
    for (int k = tid * 4; k < cnt; k += 1024) {
        if (k + 3 < cnt) {
            int4 d4 = *(const int4*)(dst + base + k);
            int4 s4 = *(const int4*)(src + base + k);
            atomicAdd(&h[d4.x >> 8], 1); atomicAdd(&h[d4.y >> 8], 1);
            atomicAdd(&h[d4.z >> 8], 1); atomicAdd(&h[d4.w >> 8], 1);
            atomicAdd(&h[NBUK + (s4.x >> 8)], 1); atomicAdd(&h[NBUK + (s4.y >> 8)], 1);
            atomicAdd(&h[NBUK + (s4.z >> 8)], 1); atomicAdd(&h[NBUK + (s4.w >> 8)], 1);
        } else {
            int kend = (k + 4 < cnt) ? k + 4 : cnt;
            for (int t = k; t < kend; ++t) {
                atomicAdd(&h[dst[base + t] >> 8], 1);
                atomicAdd(&h[NBUK + (src[base + t] >> 8)], 1);
            }
        }
    }
    __syncthreads();
    int* pb = per_block + (size_t)blockIdx.x * (2 * NBUK);
    for (int j = tid; j < 2 * NBUK; j += 256) pb[j] = h[j];
}

// ---- scanA: per-column exclusive prefix over blocks (in place) + column totals ----
__global__ __launch_bounds__(64) void scanA_kernel(int* __restrict__ per_block,
                                                   int* __restrict__ total, int nblk) {
    int j = blockIdx.x * 64 + (int)threadIdx.x;
    if (j >= 2 * NBUK) return;
    int pref = 0;
    for (int bk = 0; bk < nblk; ++bk) {
        int idx = bk * (2 * NBUK) + j;
        int v = per_block[idx];
        per_block[idx] = pref;
        pref += v;
    }
    total[j] = pref;
}

// ---- scanB: exclusive-scan bucket totals for dst and src halves ----
__global__ __launch_bounds__(512) void scanB_kernel(const int* __restrict__ total,
                                                    int* __restrict__ cb_dst,
                                                    int* __restrict__ cb_src) {
    __shared__ int s[512];
    int tid = (int)threadIdx.x;
    for (int half = 0; half < 2; ++half) {
        int v = (tid < NBUK) ? total[half * NBUK + tid] : 0;
        s[tid] = v;
        __syncthreads();
        for (int off = 1; off < 512; off <<= 1) {
            int t = (tid >= off) ? s[tid - off] : 0;
            __syncthreads();
            s[tid] += t;
            __syncthreads();
        }
        int* cb = half ? cb_src : cb_dst;
        if (tid < NBUK) cb[tid] = s[tid] - v;
        if (tid == NBUK - 1) cb[NBUK] = s[tid];
        __syncthreads();
    }
}

// ---- phase2: scatter edges to bucket order via LDS cursors (no global atomics) ----
__global__ __launch_bounds__(256) void phase2_kernel(const int* __restrict__ src,
                                                     const int* __restrict__ dst,
                                                     const int* __restrict__ per_block,
                                                     const int* __restrict__ cb_dst,
                                                     const int* __restrict__ cb_src,
                                                     int* __restrict__ pairs,
                                                     unsigned char* __restrict__ skeys, int E) {
    __shared__ int lcur[2 * NBUK];
    int tid = (int)threadIdx.x;
    const int* pbb = per_block + (size_t)blockIdx.x * (2 * NBUK);
    for (int j = tid; j < 2 * NBUK; j += 256)
        lcur[j] = pbb[j] + (j < NBUK ? cb_dst[j] : cb_src[j - NBUK]);
    __syncthreads();
    int base = blockIdx.x * CHUNK;
    int cnt = min(CHUNK, E - base);
    for (int k = tid * 4; k < cnt; k += 1024) {
        if (k + 3 < cnt) {
            int4 d4 = *(const int4*)(dst + base + k);
            int4 s4 = *(const int4*)(src + base + k);
            int p;
            p = atomicAdd(&lcur[d4.x >> 8], 1); pairs[p] = (s4.x << 8) | (d4.x & 255);
            p = atomicAdd(&lcur[d4.y >> 8], 1); pairs[p] = (s4.y << 8) | (d4.y & 255);
            p = atomicAdd(&lcur[d4.z >> 8], 1); pairs[p] = (s4.z << 8) | (d4.z & 255);
            p = atomicAdd(&lcur[d4.w >> 8], 1); pairs[p] = (s4.w << 8) | (d4.w & 255);
            p = atomicAdd(&lcur[NBUK + (s4.x >> 8)], 1); skeys[p] = (unsigned char)(s4.x & 255);
            p = atomicAdd(&lcur[NBUK + (s4.y >> 8)], 1); skeys[p] = (unsigned char)(s4.y & 255);
            p = atomicAdd(&lcur[NBUK + (s4.z >> 8)], 1); skeys[p] = (unsigned char)(s4.z & 255);
            p = atomicAdd(&lcur[NBUK + (s4.w >> 8)], 1); skeys[p] = (unsigned char)(s4.w & 255);
        } else {
            int kend = (k + 4 < cnt) ? k + 4 : cnt;
            for (int t = k; t < kend; ++t) {
                int dv = dst[base + t], sv = src[base + t];
                int p = atomicAdd(&lcur[dv >> 8], 1);
                pairs[p] = (sv << 8) | (dv & 255);
                p = atomicAdd(&lcur[NBUK + (sv >> 8)], 1);
                skeys[p] = (unsigned char)(sv & 255);
            }
        }
    }
}

// ---- finalize: per bucket, dinv from src-keys; row_ptr + col from dst-pairs ----
__global__ __launch_bounds__(256) void finalize_csr_kernel(const int* __restrict__ pairs,
                                                           const unsigned char* __restrict__ skeys,
                                                           const int* __restrict__ cb_dst,
                                                           const int* __restrict__ cb_src,
                                                           int* __restrict__ row_ptr,
                                                           int* __restrict__ col,
                                                           float* __restrict__ dinv, int N) {
    __shared__ int fine[256];
    __shared__ int lcur[256];
    __shared__ int wtot[4], wexcl[4];
    int b = (int)blockIdx.x;
    int tid = (int)threadIdx.x, lane = tid & 63, wv = tid >> 6;
    int g = b * 256 + tid;

    // out-degree -> dinv
    fine[tid] = 0;
    __syncthreads();
    int sb0 = cb_src[b], sb1 = cb_src[b + 1];
    for (int i = sb0 + tid; i < sb1; i += 256) atomicAdd(&fine[skeys[i]], 1);
    __syncthreads();
    if (g < N) dinv[g] = 1.0f / fmaxf((float)fine[tid], 1.0f);
    __syncthreads();

    // in-degree fine hist
    fine[tid] = 0;
    __syncthreads();
    int cb0 = cb_dst[b], cb1 = cb_dst[b + 1];
    for (int i = cb0 + tid; i < cb1; i += 256) atomicAdd(&fine[pairs[i] & 255], 1);
    __syncthreads();
    // exclusive scan of fine[256]
    int v = fine[tid], x = v;
#pragma unroll
    for (int d = 1; d < 64; d <<= 1) {
        int t = __shfl_up(x, d);
        if (lane >= d) x += t;
    }
    if (lane == 63) wtot[wv] = x;
    __syncthreads();
    if (tid == 0) {
        int a = 0;
#pragma unroll
        for (int k = 0; k < 4; ++k) { wexcl[k] = a; a += wtot[k]; }
    }
    __syncthreads();
    int excl = x - v + wexcl[wv];
    if (g <= N) row_ptr[g] = cb0 + excl;
    lcur[tid] = cb0 + excl;
    __syncthreads();
    // scatter col within bucket
    for (int i = cb0 + tid; i < cb1; i += 256) {
        int p = pairs[i];
        int pos = atomicAdd(&lcur[p & 255], 1);
        col[pos] = p >> 8;
    }
}

// ---- prescale: hs[n][:] = feat[n][:] * dinv[n] ----
__global__ __launch_bounds__(256) void prescale_kernel(const float* __restrict__ feat,
                                                       const float* __restrict__ dinv,
                                                       float* __restrict__ hs, int total4) {
    int i = blockIdx.x * 256 + threadIdx.x;
    if (i >= total4) return;
    int n = i >> 4;
    float sc = dinv[n];
    float4 v = ((const float4*)feat)[i];
    v.x *= sc; v.y *= sc; v.z *= sc; v.w *= sc;
    ((float4*)hs)[i] = v;
}

// ---- fused gather + GEMM (+ column-sum on final layer) ----
__global__ __launch_bounds__(256) void fused_kernel(const float* __restrict__ hs_in,
                                                    const int* __restrict__ row_ptr,
                                                    const int* __restrict__ col,
                                                    const float* __restrict__ W,
                                                    const float* __restrict__ bias,
                                                    const float* __restrict__ dinv,
                                                    float* __restrict__ out,
                                                    float* __restrict__ msum,
                                                    int N, int mode) {
    int tid = (int)threadIdx.x;
    int lane = tid & 63;
    int wv = tid >> 6;
    int g = tid >> 4, q = tid & 15;

    float Wreg[64];
#pragma unroll
    for (int k = 0; k < 64; ++k) Wreg[k] = W[k * 64 + lane];
    float breg = bias[lane];

    __shared__ float aggT[16][64];
    float colacc = 0.0f;

    int ntiles = (N + 15) >> 4;
    for (int tile = blockIdx.x; tile < ntiles; tile += gridDim.x) {
        int node_g = tile * 16 + g;
        float4 a0 = make_float4(0.f, 0.f, 0.f, 0.f);
        float4 a1 = make_float4(0.f, 0.f, 0.f, 0.f);
        float4 a2 = make_float4(0.f, 0.f, 0.f, 0.f);
        float4 a3 = make_float4(0.f, 0.f, 0.f, 0.f);
        if (node_g < N) {
            int beg = row_ptr[node_g], end = row_ptr[node_g + 1];
            int j = beg;
            for (; j + 3 < end; j += 4) {
                int s0 = col[j], s1 = col[j + 1], s2 = col[j + 2], s3 = col[j + 3];
                float4 v0 = *(const float4*)(hs_in + (size_t)s0 * D + q * 4);
                float4 v1 = *(const float4*)(hs_in + (size_t)s1 * D + q * 4);
                float4 v2 = *(const float4*)(hs_in + (size_t)s2 * D + q * 4);
                float4 v3 = *(const float4*)(hs_in + (size_t)s3 * D + q * 4);
                a0.x += v0.x; a0.y += v0.y; a0.z += v0.z; a0.w += v0.w;
                a1.x += v1.x; a1.y += v1.y; a1.z += v1.z; a1.w += v1.w;
                a2.x += v2.x; a2.y += v2.y; a2.z += v2.z; a2.w += v2.w;
                a3.x += v3.x; a3.y += v3.y; a3.z += v3.z; a3.w += v3.w;
            }
            for (; j < end; ++j) {
                int s0 = col[j];
                float4 v0 = *(const float4*)(hs_in + (size_t)s0 * D + q * 4);
                a0.x += v0.x; a0.y += v0.y; a0.z += v0.z; a0.w += v0.w;
            }
            a0.x += a1.x; a0.y += a1.y; a0.z += a1.z; a0.w += a1.w;
            a2.x += a3.x; a2.y += a3.y; a2.z += a3.z; a2.w += a3.w;
            a0.x += a2.x; a0.y += a2.y; a0.z += a2.z; a0.w += a2.w;
        }
        *(float4*)(&aggT[g][q * 4]) = a0;
        __syncthreads();

#pragma unroll
        for (int rr = 0; rr < 4; ++rr) {
            int r = wv * 4 + rr;
            int node = tile * 16 + r;
            if (node < N) {
                float acc = breg;
                const float4* Ar = (const float4*)(&aggT[r][0]);
#pragma unroll
                for (int k4 = 0; k4 < 16; ++k4) {
                    float4 av = Ar[k4];
                    acc = fmaf(av.x, Wreg[k4 * 4 + 0], acc);
                    acc = fmaf(av.y, Wreg[k4 * 4 + 1], acc);
                    acc = fmaf(av.z, Wreg[k4 * 4 + 2], acc);
                    acc = fmaf(av.w, Wreg[k4 * 4 + 3], acc);
                }
                if (mode == 0) {
                    acc = fmaxf(acc, 0.0f) * dinv[node];
                } else {
                    colacc += acc;
                }
                out[(size_t)node * D + lane] = acc;
            }
        }
        __syncthreads();
    }

    if (mode == 1) {
        __shared__ float red[256];
        red[tid] = colacc;
        __syncthreads();
        if (wv == 0) {
            float s = red[lane] + red[64 + lane] + red[128 + lane] + red[192 + lane];
            atomicAdd(&msum[lane], s);
        }
    }
}

__global__ void finalize_kernel(const float* __restrict__ msum, float* __restrict__ outMean,
                                float invN) {
    outMean[threadIdx.x] = msum[threadIdx.x] * invN;
}

extern "C" void kernel_launch(void* const* d_in, const int* in_sizes, int n_in,
                              void* d_out, int out_size, void* d_ws, size_t ws_size,
                              hipStream_t stream) {
    const float* feat = (const float*)d_in[0];
    const int* src = (const int*)d_in[1];
    const int* dst = (const int*)d_in[2];
    const float* W0 = (const float*)d_in[3];
    const float* b0 = (const float*)d_in[4];
    const float* W1 = (const float*)d_in[5];
    const float* b1 = (const float*)d_in[6];
    const float* W2 = (const float*)d_in[7];
    const float* b2 = (const float*)d_in[8];

    const int N = in_sizes[0] / D;  // 100000
    const int E = in_sizes[1];      // 1600000
    float* out = (float*)d_out;     // [N*D + D] floats

    const int NBLK = (E + CHUNK - 1) / CHUNK;  // 196

    // workspace layout (int units), 16B-aligned offsets; NA = padded N+1
    int* wsi = (int*)d_ws;
    const size_t NA = 100352;
    int*   row_ptr  = wsi;                       // NA
    float* dinv     = (float*)(wsi + NA);        // NA
    float* msum     = (float*)(wsi + 2 * NA);    // 64 (pad 256)
    int*   total    = wsi + 2 * NA + 256;        // 782 (pad 1024)
    int*   cb_dst   = wsi + 2 * NA + 1280;       // 392 (pad 512)
    int*   cb_src   = wsi + 2 * NA + 1792;       // 392 (pad 512)
    int*   per_blk  = wsi + 2 * NA + 2304;       // NBLK*782 (pad 153600)
    int*   pairs    = wsi + 2 * NA + 155904;     // E
    unsigned char* skeys = (unsigned char*)(pairs + (size_t)E);  // E bytes (pad E ints/4 -> 400000 ints)
    int*   col      = pairs + (size_t)E + 400000;                // E
    float* hsA      = (float*)(col + (size_t)E);                 // N*D
    float* hsB      = hsA + (size_t)N * D;                       // N*D

    hipMemsetAsync(msum, 0, sizeof(float) * D, stream);

    phase1_kernel<<<NBLK, 256, 0, stream>>>(src, dst, per_blk, E);
    scanA_kernel<<<(2 * NBUK + 63) / 64, 64, 0, stream>>>(per_blk, total, NBLK);
    scanB_kernel<<<1, 512, 0, stream>>>(total, cb_dst, cb_src);
    phase2_kernel<<<NBLK, 256, 0, stream>>>(src, dst, per_blk, cb_dst, cb_src, pairs, skeys, E);
    finalize_csr_kernel<<<NBUK, 256, 0, stream>>>(pairs, skeys, cb_dst, cb_src, row_ptr, col, dinv, N);

    prescale_kernel<<<(N * 16 + 255) / 256, 256, 0, stream>>>(feat, dinv, hsA, N * 16);

    const int FG = 1024;
    fused_kernel<<<FG, 256, 0, stream>>>(hsA, row_ptr, col, W0, b0, dinv, hsB, msum, N, 0);
    fused_kernel<<<FG, 256, 0, stream>>>(hsB, row_ptr, col, W1, b1, dinv, hsA, msum, N, 0);
    fused_kernel<<<FG, 256, 0, stream>>>(hsA, row_ptr, col, W2, b2, dinv, out, msum, N, 1);

    finalize_kernel<<<1, 64, 0, stream>>>(msum, out + (size_t)N * D, 1.0f / (float)N);
}